// Round 1
// baseline (879.634 us; speedup 1.0000x reference)
//
#include <hip/hip_runtime.h>
#include <hip/hip_bf16.h>

typedef unsigned short ushort_t;
using f32x4  = __attribute__((ext_vector_type(4))) float;
using bf16x8 = __attribute__((ext_vector_type(8))) short;

#define N_PIX 4096

static __device__ __forceinline__ unsigned short f2bf(float f) {
  unsigned int u = __builtin_bit_cast(unsigned int, f);
  u += 0x7FFFu + ((u >> 16) & 1u);   // round-to-nearest-even
  return (unsigned short)(u >> 16);
}

// ---------------------------------------------------------------------------
// Kernel 1: cam_enc = conv3x3(cam_bev, cam_enc_w) + b   [80ch -> 126ch, 64x64]
// grid (16, 126), block 256. One thread per output pixel; wave = one row of x
// so input reads coalesce; weights uniform per block (blockIdx.y) -> scalar.
// ---------------------------------------------------------------------------
__global__ __launch_bounds__(256) void conv_cam_enc_k(
    const float* __restrict__ in, const float* __restrict__ w,
    const float* __restrict__ b, float* __restrict__ out) {
  int n  = blockIdx.x * 256 + threadIdx.x;
  int co = blockIdx.y;
  int y = n >> 6, x = n & 63;
  float acc = b[co];
  const float* wp = w + co * 720;           // 80*9
  for (int ci = 0; ci < 80; ++ci) {
    const float* ip = in + ci * N_PIX;
    const float* wc = wp + ci * 9;
    #pragma unroll
    for (int ky = 0; ky < 3; ++ky) {
      int yy = y + ky - 1;
      if ((unsigned)yy >= 64u) continue;
      #pragma unroll
      for (int kx = 0; kx < 3; ++kx) {
        int xx = x + kx - 1;
        if ((unsigned)xx >= 64u) continue;
        acc += ip[yy * 64 + xx] * wc[ky * 3 + kx];
      }
    }
  }
  out[co * N_PIX + n] = acc;
}

// ---------------------------------------------------------------------------
// Kernel 2: QKV projections -> bf16.
//   lidQK/camQK: [n][256] bf16  (q cols 0..127, k cols 128..255; col = h*32+d)
//   camV/lidV:   [128][4096] bf16  (d-major, ready for V^T LDS tiles)
// grid (16, 192): 4 output columns per block (regions are 256/256/128/128,
// all multiples of 4, so a block never straddles tensors).
// ---------------------------------------------------------------------------
__global__ __launch_bounds__(256) void qkv_k(
    const float* __restrict__ lidar_bev, const float* __restrict__ cam_enc,
    const float* __restrict__ lid_qk_w, const float* __restrict__ cam_qk_w,
    const float* __restrict__ cam_v_w, const float* __restrict__ lid_v_w,
    ushort_t* __restrict__ lidQK, ushort_t* __restrict__ camQK,
    ushort_t* __restrict__ camV, ushort_t* __restrict__ lidV) {
  int n    = blockIdx.x * 256 + threadIdx.x;
  int col0 = blockIdx.y * 4;
  const float* X; const float* W; int wr;
  if (col0 < 256)      { X = lidar_bev; W = lid_qk_w; wr = col0; }
  else if (col0 < 512) { X = cam_enc;   W = cam_qk_w; wr = col0 - 256; }
  else if (col0 < 640) { X = cam_enc;   W = cam_v_w;  wr = col0 - 512; }
  else                 { X = lidar_bev; W = lid_v_w;  wr = col0 - 640; }
  const float* w0 = W + wr * 126;
  float a0 = 0.f, a1 = 0.f, a2 = 0.f, a3 = 0.f;
  for (int c = 0; c < 126; ++c) {
    float xv = X[c * N_PIX + n];            // coalesced (n per lane)
    a0 += xv * w0[c];
    a1 += xv * w0[126 + c];
    a2 += xv * w0[252 + c];
    a3 += xv * w0[378 + c];
  }
  if (col0 < 512) {
    ushort_t* o = (col0 < 256) ? (lidQK + (size_t)n * 256 + col0)
                               : (camQK + (size_t)n * 256 + (col0 - 256));
    ushort4 p; p.x = f2bf(a0); p.y = f2bf(a1); p.z = f2bf(a2); p.w = f2bf(a3);
    *(ushort4*)o = p;
  } else {
    ushort_t* o = (col0 < 640) ? (camV + (size_t)(col0 - 512) * N_PIX + n)
                               : (lidV + (size_t)(col0 - 640) * N_PIX + n);
    o[0] = f2bf(a0); o[N_PIX] = f2bf(a1); o[2 * N_PIX] = f2bf(a2); o[3 * N_PIX] = f2bf(a3);
  }
}

// ---------------------------------------------------------------------------
// Kernel 3: bf16 MFMA flash attention. One attn row-pass applied to BOTH value
// tensors (cam_v | lid_v share the softmax'd P).
// grid (64 qblocks, 4 heads, 2 attns), block 256 = 4 waves.
// QBLK=64 (16 rows/wave), KBLK=64.
// mfma_f32_16x16x32_bf16:  A: lane m=l&15, k=(l>>4)*8+j ; B: n=l&15, k likewise
//                          C/D: col=l&15, row=(l>>4)*4+reg   (HW-verified)
// LDS strides: 40 ushort (80B) for 32-wide rows, 72 ushort (144B) for 64-wide
// rows -> odd multiples of 16B, b128 fragment reads <=2-way per 16-lane phase.
// ---------------------------------------------------------------------------
__global__ __launch_bounds__(256) void flash_attn_mfma(
    const ushort_t* __restrict__ lidQK, const ushort_t* __restrict__ camQK,
    const ushort_t* __restrict__ camV, const ushort_t* __restrict__ lidV,
    float* __restrict__ O1, float* __restrict__ O2,
    float* __restrict__ O3, float* __restrict__ O4) {
  const int i0   = blockIdx.x * 64;
  const int h    = blockIdx.y;
  const int attn = blockIdx.z;
  const ushort_t* QK = attn ? camQK : lidQK;
  float* Ocam = attn ? O3 : O1;
  float* Olid = attn ? O4 : O2;
  const float scale = 0.08908708063747479f;   // 126^-0.5

  __shared__ __align__(16) ushort_t Qs[64 * 40];
  __shared__ __align__(16) ushort_t Ks[64 * 40];
  __shared__ __align__(16) ushort_t Vt[64 * 72];   // rows 0..31 cam d, 32..63 lid d
  __shared__ __align__(16) ushort_t Ps[64 * 72];   // per-wave 16-row bands

  const int tid = threadIdx.x;
  const int w = tid >> 6;
  const int l = tid & 63;
  const int m = l & 15;
  const int g = l >> 4;

  // stage Q tile [64 q][32 d] as [q][d]
  {
    int row = tid >> 2, part = tid & 3;
    uint4 v = *(const uint4*)(QK + (size_t)(i0 + row) * 256 + h * 32 + part * 8);
    *(uint4*)(&Qs[row * 40 + part * 8]) = v;
  }
  __syncthreads();
  bf16x8 qfrag = *(const bf16x8*)(&Qs[(w * 16 + m) * 40 + g * 8]);

  f32x4 Oacc[4];
  #pragma unroll
  for (int t = 0; t < 4; ++t) Oacc[t] = (f32x4){0.f, 0.f, 0.f, 0.f};
  float mrun[4], lrun[4];
  #pragma unroll
  for (int r = 0; r < 4; ++r) { mrun[r] = -1e30f; lrun[r] = 0.f; }

  for (int j0 = 0; j0 < N_PIX; j0 += 64) {
    __syncthreads();   // previous iteration's PV reads done before restaging
    {   // stage K tile [64 key][32 d]
      int row = tid >> 2, part = tid & 3;
      uint4 v = *(const uint4*)(QK + (size_t)(j0 + row) * 256 + 128 + h * 32 + part * 8);
      *(uint4*)(&Ks[row * 40 + part * 8]) = v;
    }
    {   // stage V^T tiles [d][key] (global is already d-major)
      int row = tid >> 3, part = tid & 7;   // row 0..31, 16B chunks of 8 keys
      uint4 vc = *(const uint4*)(camV + (size_t)(h * 32 + row) * N_PIX + j0 + part * 8);
      *(uint4*)(&Vt[row * 72 + part * 8]) = vc;
      uint4 vl = *(const uint4*)(lidV + (size_t)(h * 32 + row) * N_PIX + j0 + part * 8);
      *(uint4*)(&Vt[(row + 32) * 72 + part * 8]) = vl;
    }
    __syncthreads();

    // S = Q K^T : wave computes its 16x64 band as 4 MFMAs
    f32x4 S[4];
    #pragma unroll
    for (int nb = 0; nb < 4; ++nb) {
      bf16x8 kb = *(const bf16x8*)(&Ks[(nb * 16 + m) * 40 + g * 8]);
      f32x4 z = (f32x4){0.f, 0.f, 0.f, 0.f};
      S[nb] = __builtin_amdgcn_mfma_f32_16x16x32_bf16(qfrag, kb, z, 0, 0, 0);
    }
    #pragma unroll
    for (int nb = 0; nb < 4; ++nb) S[nb] *= scale;

    // online softmax; lane owns rows g*4+r, key cols live across lanes m (bits 0..3)
    float corr[4];
    #pragma unroll
    for (int r = 0; r < 4; ++r) {
      float mx = fmaxf(fmaxf(S[0][r], S[1][r]), fmaxf(S[2][r], S[3][r]));
      #pragma unroll
      for (int sh = 1; sh < 16; sh <<= 1) mx = fmaxf(mx, __shfl_xor(mx, sh));
      float mn = fmaxf(mrun[r], mx);
      corr[r] = __expf(mrun[r] - mn);
      float ps = 0.f;
      #pragma unroll
      for (int nb = 0; nb < 4; ++nb) {
        float p = __expf(S[nb][r] - mn);
        S[nb][r] = p;
        ps += p;
      }
      #pragma unroll
      for (int sh = 1; sh < 16; sh <<= 1) ps += __shfl_xor(ps, sh);
      lrun[r] = lrun[r] * corr[r] + ps;
      mrun[r] = mn;
    }

    // P -> LDS bf16 in A-operand layout [q][key] (wave-private band, no barrier)
    #pragma unroll
    for (int nb = 0; nb < 4; ++nb)
      #pragma unroll
      for (int r = 0; r < 4; ++r)
        Ps[(w * 16 + g * 4 + r) * 72 + nb * 16 + m] = f2bf(S[nb][r]);

    #pragma unroll
    for (int t = 0; t < 4; ++t)
      #pragma unroll
      for (int r = 0; r < 4; ++r) Oacc[t][r] *= corr[r];

    // PV: O[16q x 16d] tiles; A-frag (P) shared across the 4 d-tiles
    #pragma unroll
    for (int ks = 0; ks < 2; ++ks) {
      bf16x8 pa = *(const bf16x8*)(&Ps[(w * 16 + m) * 72 + ks * 32 + g * 8]);
      #pragma unroll
      for (int t = 0; t < 4; ++t) {
        bf16x8 vb = *(const bf16x8*)(&Vt[(t * 16 + m) * 72 + ks * 32 + g * 8]);
        Oacc[t] = __builtin_amdgcn_mfma_f32_16x16x32_bf16(pa, vb, Oacc[t], 0, 0, 0);
      }
    }
  }

  // epilogue: normalize, write O buffers [128][4096] f32 (col = h*32+d)
  #pragma unroll
  for (int t = 0; t < 4; ++t) {
    float* Obuf = (t < 2) ? Ocam : Olid;
    int d = h * 32 + (t & 1) * 16 + m;
    #pragma unroll
    for (int r = 0; r < 4; ++r) {
      int n = i0 + w * 16 + g * 4 + r;
      Obuf[(size_t)d * N_PIX + n] = Oacc[t][r] / lrun[r];
    }
  }
}

// ---------------------------------------------------------------------------
// Kernel 4: output projections + bias + residuals -> fused [504][4096] f32.
//   ch 0..125  : cam_enc   + O3 @ lidar_proj  (cam_bev_c)
//   ch 126..251: cam_enc   + O1 @ cam_proj    (cam_bev_l)
//   ch 252..377: lidar_bev + O4 @ lidar_proj  (lidar_bev_c)
//   ch 378..503: lidar_bev + O2 @ lidar_proj  (lidar_bev_l)
// grid (16, 63): 2 channels per block to halve O-tensor re-reads.
// ---------------------------------------------------------------------------
__global__ __launch_bounds__(256) void proj_fuse_k(
    const float* __restrict__ O1, const float* __restrict__ O2,
    const float* __restrict__ O3, const float* __restrict__ O4,
    const float* __restrict__ cam_proj_w, const float* __restrict__ cam_proj_b,
    const float* __restrict__ lid_proj_w, const float* __restrict__ lid_proj_b,
    const float* __restrict__ cam_enc, const float* __restrict__ lidar_bev,
    float* __restrict__ fused) {
  int n  = blockIdx.x * 256 + threadIdx.x;
  int c0 = blockIdx.y * 2;
  float a00=0,a01=0,a02=0,a03=0, a10=0,a11=0,a12=0,a13=0;
  for (int k = 0; k < 128; ++k) {
    float o1 = O1[(size_t)k * N_PIX + n];
    float o2 = O2[(size_t)k * N_PIX + n];
    float o3 = O3[(size_t)k * N_PIX + n];
    float o4 = O4[(size_t)k * N_PIX + n];
    float wl0 = lid_proj_w[c0 * 128 + k],       wc0 = cam_proj_w[c0 * 128 + k];
    float wl1 = lid_proj_w[(c0 + 1) * 128 + k], wc1 = cam_proj_w[(c0 + 1) * 128 + k];
    a00 += o3 * wl0; a01 += o1 * wc0; a02 += o4 * wl0; a03 += o2 * wl0;
    a10 += o3 * wl1; a11 += o1 * wc1; a12 += o4 * wl1; a13 += o2 * wl1;
  }
  {
    int c = c0;
    float ce = cam_enc[c * N_PIX + n], lb = lidar_bev[c * N_PIX + n];
    float bl = lid_proj_b[c], bc = cam_proj_b[c];
    fused[(size_t)(0   + c) * N_PIX + n] = ce + a00 + bl;
    fused[(size_t)(126 + c) * N_PIX + n] = ce + a01 + bc;
    fused[(size_t)(252 + c) * N_PIX + n] = lb + a02 + bl;
    fused[(size_t)(378 + c) * N_PIX + n] = lb + a03 + bl;
  }
  {
    int c = c0 + 1;
    float ce = cam_enc[c * N_PIX + n], lb = lidar_bev[c * N_PIX + n];
    float bl = lid_proj_b[c], bc = cam_proj_b[c];
    fused[(size_t)(0   + c) * N_PIX + n] = ce + a10 + bl;
    fused[(size_t)(126 + c) * N_PIX + n] = ce + a11 + bc;
    fused[(size_t)(252 + c) * N_PIX + n] = lb + a12 + bl;
    fused[(size_t)(378 + c) * N_PIX + n] = lb + a13 + bl;
  }
}

// ---------------------------------------------------------------------------
// Kernel 5: out = conv3x3(fused, fuser_w)  [504ch -> 126ch], no bias.
// grid (16, 63): 2 output channels per block (input tile reused in-register).
// ---------------------------------------------------------------------------
__global__ __launch_bounds__(256) void conv_fuser_k(
    const float* __restrict__ fused, const float* __restrict__ w,
    float* __restrict__ out) {
  int n   = blockIdx.x * 256 + threadIdx.x;
  int co0 = blockIdx.y * 2;
  int y = n >> 6, x = n & 63;
  float a0 = 0.f, a1 = 0.f;
  for (int ci = 0; ci < 504; ++ci) {
    const float* ip  = fused + (size_t)ci * N_PIX;
    const float* wp0 = w + ((size_t)co0 * 504 + ci) * 9;
    const float* wp1 = wp0 + 504 * 9;
    #pragma unroll
    for (int ky = 0; ky < 3; ++ky) {
      int yy = y + ky - 1;
      if ((unsigned)yy >= 64u) continue;
      #pragma unroll
      for (int kx = 0; kx < 3; ++kx) {
        int xx = x + kx - 1;
        if ((unsigned)xx >= 64u) continue;
        float v = ip[yy * 64 + xx];
        a0 += v * wp0[ky * 3 + kx];
        a1 += v * wp1[ky * 3 + kx];
      }
    }
  }
  out[(size_t)co0 * N_PIX + n]       = a0;
  out[(size_t)(co0 + 1) * N_PIX + n] = a1;
}

// ---------------------------------------------------------------------------
extern "C" void kernel_launch(void* const* d_in, const int* in_sizes, int n_in,
                              void* d_out, int out_size, void* d_ws, size_t ws_size,
                              hipStream_t stream) {
  (void)in_sizes; (void)n_in; (void)out_size; (void)ws_size;
  const float* lidar_bev  = (const float*)d_in[0];
  const float* cam_bev    = (const float*)d_in[1];
  const float* cam_enc_w  = (const float*)d_in[2];
  const float* cam_enc_b  = (const float*)d_in[3];
  const float* cam_v_w    = (const float*)d_in[4];
  const float* cam_qk_w   = (const float*)d_in[5];
  const float* cam_proj_w = (const float*)d_in[6];
  const float* cam_proj_b = (const float*)d_in[7];
  const float* lid_v_w    = (const float*)d_in[8];
  const float* lid_qk_w   = (const float*)d_in[9];
  const float* lid_proj_w = (const float*)d_in[10];
  const float* lid_proj_b = (const float*)d_in[11];
  const float* fuser_w    = (const float*)d_in[12];
  float* out = (float*)d_out;

  char* p = (char*)d_ws;
  float* cam_enc = (float*)p;  p += (size_t)516096 * 4;          // [126][4096]
  float* fused   = (float*)p;  p += (size_t)2064384 * 4;         // [504][4096]
  float* O1 = (float*)p;       p += (size_t)524288 * 4;          // [128][4096] each
  float* O2 = (float*)p;       p += (size_t)524288 * 4;
  float* O3 = (float*)p;       p += (size_t)524288 * 4;
  float* O4 = (float*)p;       p += (size_t)524288 * 4;
  ushort_t* lidQK = (ushort_t*)p; p += (size_t)1048576 * 2;      // [4096][256] bf16
  ushort_t* camQK = (ushort_t*)p; p += (size_t)1048576 * 2;
  ushort_t* camV  = (ushort_t*)p; p += (size_t)524288 * 2;       // [128][4096] bf16
  ushort_t* lidV  = (ushort_t*)p; p += (size_t)524288 * 2;

  conv_cam_enc_k<<<dim3(16, 126), 256, 0, stream>>>(cam_bev, cam_enc_w, cam_enc_b, cam_enc);
  qkv_k<<<dim3(16, 192), 256, 0, stream>>>(lidar_bev, cam_enc, lid_qk_w, cam_qk_w,
                                           cam_v_w, lid_v_w, lidQK, camQK, camV, lidV);
  flash_attn_mfma<<<dim3(64, 4, 2), 256, 0, stream>>>(lidQK, camQK, camV, lidV, O1, O2, O3, O4);
  proj_fuse_k<<<dim3(16, 63), 256, 0, stream>>>(O1, O2, O3, O4, cam_proj_w, cam_proj_b,
                                                lid_proj_w, lid_proj_b, cam_enc, lidar_bev, fused);
  conv_fuser_k<<<dim3(16, 63), 256, 0, stream>>>(fused, fuser_w, out);
}

// Round 2
// 261.776 us; speedup vs baseline: 3.3603x; 3.3603x over previous
//
#include <hip/hip_runtime.h>
#include <hip/hip_bf16.h>

typedef unsigned short ushort_t;
using f32x4  = __attribute__((ext_vector_type(4))) float;
using bf16x8 = __attribute__((ext_vector_type(8))) short;

#define N_PIX 4096

static __device__ __forceinline__ unsigned short f2bf(float f) {
  unsigned int u = __builtin_bit_cast(unsigned int, f);
  u += 0x7FFFu + ((u >> 16) & 1u);   // round-to-nearest-even
  return (unsigned short)(u >> 16);
}

typedef union {
  uint4 u4;
  unsigned long long q[2];
  bf16x8 v;
} fragU;

#define LDS_U32(p) ((unsigned)(uintptr_t)((__attribute__((address_space(3))) void*)(p)))

// ---------------------------------------------------------------------------
// zero_span: zero a contiguous byte span (uint4 granularity)
// ---------------------------------------------------------------------------
__global__ __launch_bounds__(256) void zero_span_k(uint4* __restrict__ p, int n16) {
  int i = blockIdx.x * 256 + threadIdx.x;
  if (i < n16) p[i] = (uint4){0u, 0u, 0u, 0u};
}

// ---------------------------------------------------------------------------
// pack_w: build bf16 weight tensors
//   Wp_c [9][128][96]  from cam_enc_w [126][80][3][3]
//   Wp_f [9][128][512] from fuser_w  [126][504][3][3]
// zero-padded in co (>=126) and ci (>=80 / >=504)
// ---------------------------------------------------------------------------
__global__ __launch_bounds__(256) void pack_w_k(
    const float* __restrict__ cam_enc_w, const float* __restrict__ fuser_w,
    ushort_t* __restrict__ Wp_c, ushort_t* __restrict__ Wp_f) {
  int idx = blockIdx.x * 256 + threadIdx.x;
  if (idx < 110592) {                     // 9*128*96
    int kk = idx / 12288, r = idx % 12288;
    int co = r / 96, ci = r % 96;
    float v = (co < 126 && ci < 80) ? cam_enc_w[(co * 80 + ci) * 9 + kk] : 0.f;
    Wp_c[idx] = f2bf(v);
  } else {
    int j = idx - 110592;
    if (j >= 589824) return;              // 9*128*512
    int kk = j / 65536, r = j % 65536;
    int co = r / 512, ci = r % 512;
    float v = (co < 126 && ci < 504) ? fuser_w[(co * 504 + ci) * 9 + kk] : 0.f;
    Wp_f[j] = f2bf(v);
  }
}

// ---------------------------------------------------------------------------
// convert_cam: cam_bev f32 [80][4096] -> camBF_main [96][66][64] (+y halo),
//                                        camBF_halo [96][66][66] (+y,x halo)
// ---------------------------------------------------------------------------
__global__ __launch_bounds__(256) void convert_cam_k(
    const float* __restrict__ cam, ushort_t* __restrict__ m,
    ushort_t* __restrict__ h) {
  int idx = blockIdx.x * 256 + threadIdx.x;   // 80*4096
  int ch = idx >> 12, n = idx & 4095;
  int y = n >> 6, x = n & 63;
  unsigned short b = f2bf(cam[idx]);
  m[ch * 4224 + (y + 1) * 64 + x] = b;
  h[ch * 4356 + (y + 1) * 66 + (x + 1)] = b;
}

// ---------------------------------------------------------------------------
// conv_mfma: implicit-GEMM 3x3 conv, one (ky,kx) tap per blockIdx.y.
// Block: 256 thr = 4 waves; output tile 64 pix x 128 co; K = CIp per tap.
// A staged global_load_lds -> LDS subtiled [k/4][m/16][4][16], read with
// ds_read_b64_tr_b16; B (weights) 16B direct loads; acc f32.
// partials arena: 9 regions of 524288 f32 ([co 128][n 4096] each).
// ---------------------------------------------------------------------------
__global__ __launch_bounds__(256) void conv_mfma_k(
    const ushort_t* __restrict__ Amain,   // [CIp][66][64]
    const ushort_t* __restrict__ Ahalo,   // [CIp][66][66]
    const ushort_t* __restrict__ Wp,      // [9][128][CIp]
    float* __restrict__ parts,            // arena
    int CIp, int ksteps) {
  __shared__ __align__(16) ushort_t Abuf[2][2048];
  const int y   = blockIdx.x;
  const int kk  = blockIdx.y;
  const int ky  = kk / 3, kx = kk - ky * 3;
  const int tid = threadIdx.x;
  const int w   = tid >> 6, l = tid & 63;
  const int lane15 = l & 15, g = l >> 4;
  const int yy1 = y + ky;                 // (y + ky - 1) + 1 halo row, in [0,65]

  // A staging source (per lane): lane covers (ci_l, pixels m0..m0+7)
  const int ci_l = w * 8 + (l >> 5) * 4 + ((l & 7) >> 1);
  const int m0   = ((l >> 3) & 3) * 16 + (l & 1) * 8;
  const ushort_t* src;
  size_t plane;
  if (kx == 1) { plane = 66 * 64; src = Amain + (size_t)ci_l * plane + yy1 * 64 + m0; }
  else         { plane = 66 * 66; src = Ahalo + (size_t)ci_l * plane + yy1 * 66 + m0 + kx; }

  // B source: lane's co row (two n-tiles at +0 and +16*CIp)
  const ushort_t* wbase = Wp + ((size_t)kk * 128 + w * 32 + lane15) * CIp + g * 8;

  // tr-read per-lane base (byte addr into Abuf[0])
  const unsigned tr_base = LDS_U32(&Abuf[0][0]) + (unsigned)(g * 1024 + lane15 * 8);

  f32x4 acc[4][2];
  #pragma unroll
  for (int q = 0; q < 4; ++q) {
    acc[q][0] = (f32x4){0.f, 0.f, 0.f, 0.f};
    acc[q][1] = (f32x4){0.f, 0.f, 0.f, 0.f};
  }

  // prologue: stage buf 0
  __builtin_amdgcn_global_load_lds(
      (const __attribute__((address_space(1))) unsigned*)src,
      (__attribute__((address_space(3))) unsigned*)(&Abuf[0][w * 512]), 16, 0, 0);
  __syncthreads();

  for (int s = 0; s < ksteps; ++s) {
    if (s + 1 < ksteps) {
      const ushort_t* srcn = src + (size_t)(s + 1) * 32 * plane;
      __builtin_amdgcn_global_load_lds(
          (const __attribute__((address_space(1))) unsigned*)srcn,
          (__attribute__((address_space(3))) unsigned*)(&Abuf[(s + 1) & 1][w * 512]), 16, 0, 0);
    }
    const ushort_t* wb = wbase + s * 32;
    fragU fb0, fb1;
    fb0.u4 = *(const uint4*)(wb);
    fb1.u4 = *(const uint4*)(wb + 16 * CIp);

    unsigned ta = tr_base + (unsigned)((s & 1) << 12);
    unsigned long long r00, r01, r10, r11, r20, r21, r30, r31;
    asm volatile("ds_read_b64_tr_b16 %0, %1 offset:0"   : "=v"(r00) : "v"(ta));
    asm volatile("ds_read_b64_tr_b16 %0, %1 offset:512" : "=v"(r01) : "v"(ta));
    asm volatile("ds_read_b64_tr_b16 %0, %1 offset:128" : "=v"(r10) : "v"(ta));
    asm volatile("ds_read_b64_tr_b16 %0, %1 offset:640" : "=v"(r11) : "v"(ta));
    asm volatile("ds_read_b64_tr_b16 %0, %1 offset:256" : "=v"(r20) : "v"(ta));
    asm volatile("ds_read_b64_tr_b16 %0, %1 offset:768" : "=v"(r21) : "v"(ta));
    asm volatile("ds_read_b64_tr_b16 %0, %1 offset:384" : "=v"(r30) : "v"(ta));
    asm volatile("ds_read_b64_tr_b16 %0, %1 offset:896" : "=v"(r31) : "v"(ta));
    asm volatile("s_waitcnt lgkmcnt(0)" ::: "memory");
    __builtin_amdgcn_sched_barrier(0);

    fragU fa;
    fa.q[0] = r00; fa.q[1] = r01;
    acc[0][0] = __builtin_amdgcn_mfma_f32_16x16x32_bf16(fa.v, fb0.v, acc[0][0], 0, 0, 0);
    acc[0][1] = __builtin_amdgcn_mfma_f32_16x16x32_bf16(fa.v, fb1.v, acc[0][1], 0, 0, 0);
    fa.q[0] = r10; fa.q[1] = r11;
    acc[1][0] = __builtin_amdgcn_mfma_f32_16x16x32_bf16(fa.v, fb0.v, acc[1][0], 0, 0, 0);
    acc[1][1] = __builtin_amdgcn_mfma_f32_16x16x32_bf16(fa.v, fb1.v, acc[1][1], 0, 0, 0);
    fa.q[0] = r20; fa.q[1] = r21;
    acc[2][0] = __builtin_amdgcn_mfma_f32_16x16x32_bf16(fa.v, fb0.v, acc[2][0], 0, 0, 0);
    acc[2][1] = __builtin_amdgcn_mfma_f32_16x16x32_bf16(fa.v, fb1.v, acc[2][1], 0, 0, 0);
    fa.q[0] = r30; fa.q[1] = r31;
    acc[3][0] = __builtin_amdgcn_mfma_f32_16x16x32_bf16(fa.v, fb0.v, acc[3][0], 0, 0, 0);
    acc[3][1] = __builtin_amdgcn_mfma_f32_16x16x32_bf16(fa.v, fb1.v, acc[3][1], 0, 0, 0);
    __syncthreads();
  }

  // store partials: co = w*32 + t*16 + lane15, n = y*64 + q*16 + g*4 + reg
  float* pout = parts + (size_t)kk * 524288 + (size_t)(w * 32 + lane15) * 4096
              + y * 64 + g * 4;
  #pragma unroll
  for (int q = 0; q < 4; ++q) {
    *(f32x4*)(pout + q * 16)               = acc[q][0];
    *(f32x4*)(pout + 16 * 4096 + q * 16)   = acc[q][1];
  }
}

// ---------------------------------------------------------------------------
// reduce9: out[co][n] = sum_kk parts[kk][co][n] (+ bias), co < 126
// grid (4, 126), block 256; f32x4 per thread.
// ---------------------------------------------------------------------------
__global__ __launch_bounds__(256) void reduce9_k(
    const float* __restrict__ parts, float* __restrict__ out,
    const float* __restrict__ bias) {
  int n4 = blockIdx.x * 256 + threadIdx.x;   // 0..1023
  int co = blockIdx.y;
  size_t off = (size_t)co * 4096 + n4 * 4;
  f32x4 s = (f32x4){0.f, 0.f, 0.f, 0.f};
  #pragma unroll
  for (int kk = 0; kk < 9; ++kk)
    s += *(const f32x4*)(parts + (size_t)kk * 524288 + off);
  if (bias) {
    float b = bias[co];
    s[0] += b; s[1] += b; s[2] += b; s[3] += b;
  }
  *(f32x4*)(out + off) = s;
}

// ---------------------------------------------------------------------------
// qkv projections -> bf16 (unchanged from R1)
// ---------------------------------------------------------------------------
__global__ __launch_bounds__(256) void qkv_k(
    const float* __restrict__ lidar_bev, const float* __restrict__ cam_enc,
    const float* __restrict__ lid_qk_w, const float* __restrict__ cam_qk_w,
    const float* __restrict__ cam_v_w, const float* __restrict__ lid_v_w,
    ushort_t* __restrict__ lidQK, ushort_t* __restrict__ camQK,
    ushort_t* __restrict__ camV, ushort_t* __restrict__ lidV) {
  int n    = blockIdx.x * 256 + threadIdx.x;
  int col0 = blockIdx.y * 4;
  const float* X; const float* W; int wr;
  if (col0 < 256)      { X = lidar_bev; W = lid_qk_w; wr = col0; }
  else if (col0 < 512) { X = cam_enc;   W = cam_qk_w; wr = col0 - 256; }
  else if (col0 < 640) { X = cam_enc;   W = cam_v_w;  wr = col0 - 512; }
  else                 { X = lidar_bev; W = lid_v_w;  wr = col0 - 640; }
  const float* w0 = W + wr * 126;
  float a0 = 0.f, a1 = 0.f, a2 = 0.f, a3 = 0.f;
  for (int c = 0; c < 126; ++c) {
    float xv = X[c * N_PIX + n];
    a0 += xv * w0[c];
    a1 += xv * w0[126 + c];
    a2 += xv * w0[252 + c];
    a3 += xv * w0[378 + c];
  }
  if (col0 < 512) {
    ushort_t* o = (col0 < 256) ? (lidQK + (size_t)n * 256 + col0)
                               : (camQK + (size_t)n * 256 + (col0 - 256));
    ushort4 p; p.x = f2bf(a0); p.y = f2bf(a1); p.z = f2bf(a2); p.w = f2bf(a3);
    *(ushort4*)o = p;
  } else {
    ushort_t* o = (col0 < 640) ? (camV + (size_t)(col0 - 512) * N_PIX + n)
                               : (lidV + (size_t)(col0 - 640) * N_PIX + n);
    o[0] = f2bf(a0); o[N_PIX] = f2bf(a1); o[2 * N_PIX] = f2bf(a2); o[3 * N_PIX] = f2bf(a3);
  }
}

// ---------------------------------------------------------------------------
// flash attention (unchanged from R1)
// ---------------------------------------------------------------------------
__global__ __launch_bounds__(256) void flash_attn_mfma(
    const ushort_t* __restrict__ lidQK, const ushort_t* __restrict__ camQK,
    const ushort_t* __restrict__ camV, const ushort_t* __restrict__ lidV,
    float* __restrict__ O1, float* __restrict__ O2,
    float* __restrict__ O3, float* __restrict__ O4) {
  const int i0   = blockIdx.x * 64;
  const int h    = blockIdx.y;
  const int attn = blockIdx.z;
  const ushort_t* QK = attn ? camQK : lidQK;
  float* Ocam = attn ? O3 : O1;
  float* Olid = attn ? O4 : O2;
  const float scale = 0.08908708063747479f;   // 126^-0.5

  __shared__ __align__(16) ushort_t Qs[64 * 40];
  __shared__ __align__(16) ushort_t Ks[64 * 40];
  __shared__ __align__(16) ushort_t Vt[64 * 72];
  __shared__ __align__(16) ushort_t Ps[64 * 72];

  const int tid = threadIdx.x;
  const int w = tid >> 6;
  const int l = tid & 63;
  const int m = l & 15;
  const int g = l >> 4;

  {
    int row = tid >> 2, part = tid & 3;
    uint4 v = *(const uint4*)(QK + (size_t)(i0 + row) * 256 + h * 32 + part * 8);
    *(uint4*)(&Qs[row * 40 + part * 8]) = v;
  }
  __syncthreads();
  bf16x8 qfrag = *(const bf16x8*)(&Qs[(w * 16 + m) * 40 + g * 8]);

  f32x4 Oacc[4];
  #pragma unroll
  for (int t = 0; t < 4; ++t) Oacc[t] = (f32x4){0.f, 0.f, 0.f, 0.f};
  float mrun[4], lrun[4];
  #pragma unroll
  for (int r = 0; r < 4; ++r) { mrun[r] = -1e30f; lrun[r] = 0.f; }

  for (int j0 = 0; j0 < N_PIX; j0 += 64) {
    __syncthreads();
    {
      int row = tid >> 2, part = tid & 3;
      uint4 v = *(const uint4*)(QK + (size_t)(j0 + row) * 256 + 128 + h * 32 + part * 8);
      *(uint4*)(&Ks[row * 40 + part * 8]) = v;
    }
    {
      int row = tid >> 3, part = tid & 7;
      uint4 vc = *(const uint4*)(camV + (size_t)(h * 32 + row) * N_PIX + j0 + part * 8);
      *(uint4*)(&Vt[row * 72 + part * 8]) = vc;
      uint4 vl = *(const uint4*)(lidV + (size_t)(h * 32 + row) * N_PIX + j0 + part * 8);
      *(uint4*)(&Vt[(row + 32) * 72 + part * 8]) = vl;
    }
    __syncthreads();

    f32x4 S[4];
    #pragma unroll
    for (int nb = 0; nb < 4; ++nb) {
      bf16x8 kb = *(const bf16x8*)(&Ks[(nb * 16 + m) * 40 + g * 8]);
      f32x4 z = (f32x4){0.f, 0.f, 0.f, 0.f};
      S[nb] = __builtin_amdgcn_mfma_f32_16x16x32_bf16(qfrag, kb, z, 0, 0, 0);
    }
    #pragma unroll
    for (int nb = 0; nb < 4; ++nb) S[nb] *= scale;

    float corr[4];
    #pragma unroll
    for (int r = 0; r < 4; ++r) {
      float mx = fmaxf(fmaxf(S[0][r], S[1][r]), fmaxf(S[2][r], S[3][r]));
      #pragma unroll
      for (int sh = 1; sh < 16; sh <<= 1) mx = fmaxf(mx, __shfl_xor(mx, sh));
      float mn = fmaxf(mrun[r], mx);
      corr[r] = __expf(mrun[r] - mn);
      float ps = 0.f;
      #pragma unroll
      for (int nb = 0; nb < 4; ++nb) {
        float p = __expf(S[nb][r] - mn);
        S[nb][r] = p;
        ps += p;
      }
      #pragma unroll
      for (int sh = 1; sh < 16; sh <<= 1) ps += __shfl_xor(ps, sh);
      lrun[r] = lrun[r] * corr[r] + ps;
      mrun[r] = mn;
    }

    #pragma unroll
    for (int nb = 0; nb < 4; ++nb)
      #pragma unroll
      for (int r = 0; r < 4; ++r)
        Ps[(w * 16 + g * 4 + r) * 72 + nb * 16 + m] = f2bf(S[nb][r]);

    #pragma unroll
    for (int t = 0; t < 4; ++t)
      #pragma unroll
      for (int r = 0; r < 4; ++r) Oacc[t][r] *= corr[r];

    #pragma unroll
    for (int ks = 0; ks < 2; ++ks) {
      bf16x8 pa = *(const bf16x8*)(&Ps[(w * 16 + m) * 72 + ks * 32 + g * 8]);
      #pragma unroll
      for (int t = 0; t < 4; ++t) {
        bf16x8 vb = *(const bf16x8*)(&Vt[(t * 16 + m) * 72 + ks * 32 + g * 8]);
        Oacc[t] = __builtin_amdgcn_mfma_f32_16x16x32_bf16(pa, vb, Oacc[t], 0, 0, 0);
      }
    }
  }

  #pragma unroll
  for (int t = 0; t < 4; ++t) {
    float* Obuf = (t < 2) ? Ocam : Olid;
    int d = h * 32 + (t & 1) * 16 + m;
    #pragma unroll
    for (int r = 0; r < 4; ++r) {
      int n = i0 + w * 16 + g * 4 + r;
      Obuf[(size_t)d * N_PIX + n] = Oacc[t][r] / lrun[r];
    }
  }
}

// ---------------------------------------------------------------------------
// proj_fuse: projections + residuals -> padded bf16 buffers for conv_mfma.
//   ch 0..125  : cam_enc   + O3 @ lidar_proj  (cam_bev_c)
//   ch 126..251: cam_enc   + O1 @ cam_proj    (cam_bev_l)
//   ch 252..377: lidar_bev + O4 @ lidar_proj  (lidar_bev_c)
//   ch 378..503: lidar_bev + O2 @ lidar_proj  (lidar_bev_l)
// ---------------------------------------------------------------------------
__global__ __launch_bounds__(256) void proj_fuse_k(
    const float* __restrict__ O1, const float* __restrict__ O2,
    const float* __restrict__ O3, const float* __restrict__ O4,
    const float* __restrict__ cam_proj_w, const float* __restrict__ cam_proj_b,
    const float* __restrict__ lid_proj_w, const float* __restrict__ lid_proj_b,
    const float* __restrict__ cam_enc, const float* __restrict__ lidar_bev,
    ushort_t* __restrict__ fm, ushort_t* __restrict__ fh) {
  int n  = blockIdx.x * 256 + threadIdx.x;
  int c0 = blockIdx.y * 2;
  int y = n >> 6, x = n & 63;
  float a00=0,a01=0,a02=0,a03=0, a10=0,a11=0,a12=0,a13=0;
  for (int k = 0; k < 128; ++k) {
    float o1 = O1[(size_t)k * N_PIX + n];
    float o2 = O2[(size_t)k * N_PIX + n];
    float o3 = O3[(size_t)k * N_PIX + n];
    float o4 = O4[(size_t)k * N_PIX + n];
    float wl0 = lid_proj_w[c0 * 128 + k],       wc0 = cam_proj_w[c0 * 128 + k];
    float wl1 = lid_proj_w[(c0 + 1) * 128 + k], wc1 = cam_proj_w[(c0 + 1) * 128 + k];
    a00 += o3 * wl0; a01 += o1 * wc0; a02 += o4 * wl0; a03 += o2 * wl0;
    a10 += o3 * wl1; a11 += o1 * wc1; a12 += o4 * wl1; a13 += o2 * wl1;
  }
  int mo = (y + 1) * 64 + x;
  int ho = (y + 1) * 66 + x + 1;
  {
    int c = c0;
    float ce = cam_enc[c * N_PIX + n], lb = lidar_bev[c * N_PIX + n];
    float bl = lid_proj_b[c], bc = cam_proj_b[c];
    unsigned short v0 = f2bf(ce + a00 + bl);
    unsigned short v1 = f2bf(ce + a01 + bc);
    unsigned short v2 = f2bf(lb + a02 + bl);
    unsigned short v3 = f2bf(lb + a03 + bl);
    fm[(0   + c) * 4224 + mo] = v0;  fh[(0   + c) * 4356 + ho] = v0;
    fm[(126 + c) * 4224 + mo] = v1;  fh[(126 + c) * 4356 + ho] = v1;
    fm[(252 + c) * 4224 + mo] = v2;  fh[(252 + c) * 4356 + ho] = v2;
    fm[(378 + c) * 4224 + mo] = v3;  fh[(378 + c) * 4356 + ho] = v3;
  }
  {
    int c = c0 + 1;
    float ce = cam_enc[c * N_PIX + n], lb = lidar_bev[c * N_PIX + n];
    float bl = lid_proj_b[c], bc = cam_proj_b[c];
    unsigned short v0 = f2bf(ce + a10 + bl);
    unsigned short v1 = f2bf(ce + a11 + bc);
    unsigned short v2 = f2bf(lb + a12 + bl);
    unsigned short v3 = f2bf(lb + a13 + bl);
    fm[(0   + c) * 4224 + mo] = v0;  fh[(0   + c) * 4356 + ho] = v0;
    fm[(126 + c) * 4224 + mo] = v1;  fh[(126 + c) * 4356 + ho] = v1;
    fm[(252 + c) * 4224 + mo] = v2;  fh[(252 + c) * 4356 + ho] = v2;
    fm[(378 + c) * 4224 + mo] = v3;  fh[(378 + c) * 4356 + ho] = v3;
  }
}

// ---------------------------------------------------------------------------
extern "C" void kernel_launch(void* const* d_in, const int* in_sizes, int n_in,
                              void* d_out, int out_size, void* d_ws, size_t ws_size,
                              hipStream_t stream) {
  (void)in_sizes; (void)n_in; (void)out_size; (void)ws_size;
  const float* lidar_bev  = (const float*)d_in[0];
  const float* cam_bev    = (const float*)d_in[1];
  const float* cam_enc_w  = (const float*)d_in[2];
  const float* cam_enc_b  = (const float*)d_in[3];
  const float* cam_v_w    = (const float*)d_in[4];
  const float* cam_qk_w   = (const float*)d_in[5];
  const float* cam_proj_w = (const float*)d_in[6];
  const float* cam_proj_b = (const float*)d_in[7];
  const float* lid_v_w    = (const float*)d_in[8];
  const float* lid_qk_w   = (const float*)d_in[9];
  const float* lid_proj_w = (const float*)d_in[10];
  const float* lid_proj_b = (const float*)d_in[11];
  const float* fuser_w    = (const float*)d_in[12];
  float* out = (float*)d_out;

  char* p = (char*)d_ws;
  // partials arena: 9 x 2,097,152 B, time-aliased with O/QK/V buffers
  float* arena = (float*)p;
  float* O1 = (float*)(p + 0);
  float* O2 = (float*)(p + 2097152);
  float* O3 = (float*)(p + 4194304);
  float* O4 = (float*)(p + 6291456);
  ushort_t* lidQK = (ushort_t*)(p + 8388608);
  ushort_t* camQK = (ushort_t*)(p + 10485760);
  ushort_t* camV  = (ushort_t*)(p + 12582912);
  ushort_t* lidV  = (ushort_t*)(p + 13631488);
  // regions 7,8 of arena: p+14680064 .. p+18874368 (scratch only)
  float*    cam_enc  = (float*)(p + 18874368);    // 126x4096 f32
  ushort_t* Wp_c     = (ushort_t*)(p + 20938752); // [9][128][96]
  ushort_t* Wp_f     = (ushort_t*)(p + 21159936); // [9][128][512]
  ushort_t* camBF_m  = (ushort_t*)(p + 22339584); // [96][66][64]
  ushort_t* camBF_h  = (ushort_t*)(p + 23150592); // [96][66][66]
  ushort_t* fusBF_m  = (ushort_t*)(p + 23986944); // [512][66][64]
  ushort_t* fusBF_h  = (ushort_t*)(p + 28312320); // [512][66][66]

  // zero the padded bf16 input buffers (contiguous span, 10,433,280 B)
  zero_span_k<<<2548, 256, 0, stream>>>((uint4*)(p + 22339584), 652080);
  pack_w_k<<<2736, 256, 0, stream>>>(cam_enc_w, fuser_w, Wp_c, Wp_f);
  convert_cam_k<<<1280, 256, 0, stream>>>(cam_bev, camBF_m, camBF_h);

  conv_mfma_k<<<dim3(64, 9), 256, 0, stream>>>(camBF_m, camBF_h, Wp_c, arena, 96, 3);
  reduce9_k<<<dim3(4, 126), 256, 0, stream>>>(arena, cam_enc, cam_enc_b);

  qkv_k<<<dim3(16, 192), 256, 0, stream>>>(lidar_bev, cam_enc, lid_qk_w, cam_qk_w,
                                           cam_v_w, lid_v_w, lidQK, camQK, camV, lidV);
  flash_attn_mfma<<<dim3(64, 4, 2), 256, 0, stream>>>(lidQK, camQK, camV, lidV, O1, O2, O3, O4);
  proj_fuse_k<<<dim3(16, 63), 256, 0, stream>>>(O1, O2, O3, O4, cam_proj_w, cam_proj_b,
                                                lid_proj_w, lid_proj_b, cam_enc, lidar_bev,
                                                fusBF_m, fusBF_h);

  conv_mfma_k<<<dim3(64, 9), 256, 0, stream>>>(fusBF_m, fusBF_h, Wp_f, arena, 512, 16);
  reduce9_k<<<dim3(4, 126), 256, 0, stream>>>(arena, out, nullptr);
}